// Round 21
// baseline (167.446 us; speedup 1.0000x reference)
//
#include <hip/hip_runtime.h>
#include <hip/hip_bf16.h>

typedef short short8 __attribute__((ext_vector_type(8)));
typedef float float4v __attribute__((ext_vector_type(4)));
typedef unsigned short ushort4v __attribute__((ext_vector_type(4)));

#define BTOT 8576
#define SEQ 288
#define NF 16
#define NB 4
#define SPN 296                 // xsN row stride (ushort)
#define XTROWS 294              // xsT rows: s=-2..291 (idx = s+2)
#define XT_USH (XTROWS * 16)    // 4704
#define XN_USH (16 * SPN)       // 4736
#define PBN (XT_USH + XN_USH)   // 9440 ush per-batch pool; cat (288*32=9216) aliases
#define WCVW 104

__device__ __forceinline__ unsigned short f2b(float f) {
    union { float f; unsigned u; } v; v.f = f;
    unsigned r = v.u + 0x7FFF + ((v.u >> 16) & 1);   // RNE
    return (unsigned short)(r >> 16);
}
__device__ __forceinline__ float b2f(unsigned short u) {
    union { unsigned u; float f; } v; v.u = ((unsigned)u) << 16; return v.f;
}

// one-time Wl/Wr fp32 -> bf16 into workspace (331,776 B)
__global__ void wcast_kernel(const float* __restrict__ a, const float* __restrict__ b,
                             unsigned short* __restrict__ o) {
    int i = blockIdx.x * 256 + threadIdx.x;     // grid 324*256 = 82944 exact
    o[i]         = f2b(a[i]);
    o[82944 + i] = f2b(b[i]);
}

template<int WPRE>
__device__ __forceinline__ short8 ldw(const unsigned short* __restrict__ wb,
                                      const float* __restrict__ wf, int idx) {
    if (WPRE) {
        return *(const short8*)&wb[idx];
    } else {
        const float* p = &wf[idx];
        float4 w0 = *(const float4*)p, w1 = *(const float4*)(p + 4);
        short8 a;
        a[0] = (short)f2b(w0.x); a[1] = (short)f2b(w0.y);
        a[2] = (short)f2b(w0.z); a[3] = (short)f2b(w0.w);
        a[4] = (short)f2b(w1.x); a[5] = (short)f2b(w1.y);
        a[6] = (short)f2b(w1.z); a[7] = (short)f2b(w1.w);
        return a;
    }
}

// B-fragments for all NB batches at K-step KK9 (0..8); same addresses serve x and mean
#define LDB(KK9, B_) do {                                                      \
    const int s0_ = (KK9) * 32;                                                \
    (B_)[0] = *(const short8*)&xsN0[li * SPN + s0_ + 8 * g];                   \
    (B_)[1] = *(const short8*)&xsN1[li * SPN + s0_ + 8 * g];                   \
    (B_)[2] = *(const short8*)&xsN2[li * SPN + s0_ + 8 * g];                   \
    (B_)[3] = *(const short8*)&xsN3[li * SPN + s0_ + 8 * g];                   \
} while (0)

// A-fragments (W rows) for this wave's t-tiles at K-step KK9
#define LDA(WT_, WF_, KK9, A_) do {                                            \
    const int s0_ = (KK9) * 32;                                                \
    _Pragma("unroll")                                                          \
    for (int m_ = 0; m_ < 3; ++m_)                                             \
        if (m_ < nt) (A_)[m_] = ldw<WPRE>(WT_, WF_, arow[m_] + s0_ + 8 * g);   \
} while (0)

#define MFK(A_, B_) do {                                                       \
    _Pragma("unroll")                                                          \
    for (int m_ = 0; m_ < 3; ++m_)                                             \
        if (m_ < nt) {                                                         \
            _Pragma("unroll")                                                  \
            for (int n_ = 0; n_ < NB; ++n_)                                    \
                acc[m_][n_] = __builtin_amdgcn_mfma_f32_16x16x32_bf16((A_)[m_], (B_)[n_], acc[m_][n_], 0, 0, 0); \
        }                                                                      \
} while (0)

// 9 K-steps, 2-deep ping-pong on A only; B read fresh (R20 showed B-pp null)
#define GEMM9(WT_, WF_) do {                                                   \
    short8 aC[3], aN[3];                                                       \
    LDA(WT_, WF_, 0, aC);                                                      \
    LDA(WT_, WF_, 1, aN);                                                      \
    _Pragma("unroll")                                                          \
    for (int kk = 0; kk < 9; ++kk) {                                           \
        short8 bb[NB];                                                         \
        LDB(kk, bb);                                                           \
        if (kk & 1) { MFK(aN, bb); if (kk < 7) LDA(WT_, WF_, kk + 2, aN); }    \
        else        { MFK(aC, bb); if (kk < 7) LDA(WT_, WF_, kk + 2, aC); }    \
    }                                                                          \
} while (0)

template<int WPRE>
__global__ __launch_bounds__(512, 4) void stconv_mfma(
    const float* __restrict__ src,
    const int*   __restrict__ eidx,
    const float* __restrict__ Wlf,
    const float* __restrict__ Wrf,
    const unsigned short* __restrict__ Wbf,
    const float* __restrict__ bgcn,
    const float* __restrict__ cw1g,
    const float* __restrict__ cw2g,
    const float* __restrict__ fcwg,
    const float* __restrict__ fcbg,
    float*       __restrict__ out)
{
    __shared__ unsigned short pool[NB * PBN];  // per batch: [xsT 4704][xsN 4736]; mean in-place; cat aliases
    __shared__ unsigned short wcv[16 * WCVW];
    __shared__ unsigned short fcwB[16 * 40];
    __shared__ unsigned short MB[16 * 40];
    __shared__ float fcb[16];
    // LDS total: 75520*2 + 3328 + 1280 + 1280 + 64 = 81,472 B <= 81,920 (2 blocks/CU)

    const int tid  = threadIdx.x;
    const int wav  = tid >> 6;            // 0..7
    const int lane = tid & 63;
    const int li   = lane & 15;
    const int g    = lane >> 4;
    const int b0   = blockIdx.x * NB;

    int bid[NB];
    #pragma unroll
    for (int n = 0; n < NB; ++n) bid[n] = (b0 + n < BTOT) ? (b0 + n) : (BTOT - 1);

    // ---- P1: zero-init ----
    for (int i = tid; i < 16 * 40; i += 512) MB[i] = 0;
    for (int i = tid; i < 16 * WCVW; i += 512) wcv[i] = 0;
    if (tid < NB * 96) {   // xsT pad rows {0,1,290..293} for all batches
        int nb2 = tid / 96, r2 = tid % 96;
        int r = r2 >> 4, f = r2 & 15;
        int row = (r < 2) ? r : 288 + r;
        pool[nb2 * PBN + row * 16 + f] = 0;
    }
    __syncthreads();

    // ---- P2: x staging as 4x4 blocks, weights, register-based adjacency ----
    {
        #pragma unroll
        for (int i = 0; i < 3; ++i) {
            int u = i * 512 + tid;            // unit = (batch, 4x4 block), NB*288 total
            if (u < NB * 288) {
                int nbu = u / 288, blk = u % 288;
                const float* srcb = src + (size_t)bid[nbu & 3] * (SEQ * NF);
                unsigned short* xsTu = pool + nbu * PBN;
                unsigned short* xsNu = pool + nbu * PBN + XT_USH;
                int s0 = (blk >> 2) * 4, f0 = (blk & 3) * 4;
                ushort4v h[4];
                #pragma unroll
                for (int r = 0; r < 4; ++r) {
                    float4 v = *(const float4*)(srcb + (s0 + r) * 16 + f0);
                    h[r][0] = f2b(v.x); h[r][1] = f2b(v.y);
                    h[r][2] = f2b(v.z); h[r][3] = f2b(v.w);
                    *(ushort4v*)&xsTu[(s0 + r + 2) * 16 + f0] = h[r];
                }
                #pragma unroll
                for (int c = 0; c < 4; ++c) {  // transposed rows: pure repack
                    ushort4v w;
                    w[0] = h[0][c]; w[1] = h[1][c]; w[2] = h[2][c]; w[3] = h[3][c];
                    *(ushort4v*)&xsNu[(f0 + c) * SPN + s0] = w;
                }
            }
        }
    }
    for (int j = tid; j < 1280; j += 512) {       // fused conv taps: T[d]=w2[d]+w1[d-1]
        int fo = j / 80, rem = j % 80, fi = rem / 5, d = rem % 5;
        float t = cw2g[(fo * 16 + fi) * 5 + d];
        if (d >= 1 && d <= 3) t += cw1g[(fo * 16 + fi) * 3 + (d - 1)];
        wcv[fo * WCVW + d * 16 + fi] = f2b(t);
    }
    if (tid < 512) fcwB[(tid >> 5) * 40 + (tid & 31)] = f2b(fcwg[tid]);
    if (tid < 16) fcb[tid] = fcbg[tid];
    // adjacency in registers: thread (d,f) counts edges, shfl-reduce for degree
    if (tid < 256) {
        const int d = tid >> 4, f = tid & 15;
        float cnt = 0.0f;
        for (int e = 0; e < 96; ++e) {
            int es = eidx[e], ed = eidx[96 + e];
            cnt += (ed == d && es == f) ? 1.0f : 0.0f;
        }
        float deg = cnt;
        #pragma unroll
        for (int off = 1; off < 16; off <<= 1) deg += __shfl_xor(deg, off);
        MB[d * 40 + f] = f2b(cnt / fmaxf(deg, 1.0f));   // cols 16..39 remain zero
    }
    __syncthreads();

    // wave -> t-tile assignment: all 18 tiles covered exactly once
    const int t2 = (wav == 0) ? 16 : ((wav == 5) ? 17 : -1);
    const int nt = (t2 >= 0) ? 3 : 2;
    const int tts[3] = {wav, wav + 8, t2};
    const int arow[3] = {(tts[0] * 16 + li) * 288, (tts[1] * 16 + li) * 288,
                         (t2 >= 0) ? ((t2 * 16 + li) * 288) : 0};

    const unsigned short* WblT = Wbf;
    const unsigned short* WbrT = Wbf + 288 * 288;
    const unsigned short* xsN0 = pool + 0 * PBN + XT_USH;
    const unsigned short* xsN1 = pool + 1 * PBN + XT_USH;
    const unsigned short* xsN2 = pool + 2 * PBN + XT_USH;
    const unsigned short* xsN3 = pool + 3 * PBN + XT_USH;

    float4v acc[3][NB];   // carries H then feat (AGPRs); the ONLY cross-phase state

    // ---- P5a: acc = Wr*x + bias (bias read from L2-cached bgcn) ----
    #pragma unroll
    for (int m = 0; m < 3; ++m)
        if (m < nt) {
            #pragma unroll
            for (int r = 0; r < 4; ++r) {
                float bv = bgcn[tts[m] * 16 + 4 * g + r];
                #pragma unroll
                for (int n = 0; n < NB; ++n) acc[m][n][r] = bv;
            }
        }
    GEMM9(WbrT, Wrf);
    __syncthreads();   // all xsN reads done -> mean may overwrite in place

    // ---- P4': mean = M * x, in-place into xsN slots (units = batch x st) ----
    {
        short8 bm = *(const short8*)&MB[li * 40 + 8 * g];
        #pragma unroll
        for (int it = 0; it < 9; ++it) {
            int u = wav + 8 * it;
            if (u < NB * 18) {
                int nbu = u / 18, st = u % 18;
                unsigned short* xsTu = pool + nbu * PBN;
                unsigned short* msNu = pool + nbu * PBN + XT_USH;
                int s0 = st * 16;
                short8 a = {0, 0, 0, 0, 0, 0, 0, 0};
                if (g < 2) a = *(const short8*)&xsTu[(s0 + li + 2) * 16 + 8 * g];
                float4v c = {0.f, 0.f, 0.f, 0.f};
                c = __builtin_amdgcn_mfma_f32_16x16x32_bf16(a, bm, c, 0, 0, 0);
                ushort4v p;
                #pragma unroll
                for (int r = 0; r < 4; ++r) p[r] = f2b(c[r]);
                *(ushort4v*)&msNu[li * SPN + s0 + 4 * g] = p;
            }
        }
    }
    __syncthreads();

    // ---- P5b: acc += Wl*mean (same B addresses) ----
    GEMM9(WblT, Wlf);

    ushort4v p5o[3][NB];
    #pragma unroll
    for (int m = 0; m < 3; ++m)
        if (m < nt) {
            #pragma unroll
            for (int n = 0; n < NB; ++n) {
                #pragma unroll
                for (int r = 0; r < 4; ++r)
                    p5o[m][n][r] = f2b(acc[m][n][r]);
            }
        }

    // ---- P6: conv via MFMA (units = batch x st), output to registers ----
    ushort4v p6o[9];
    {
        short8 cb0 = *(const short8*)&wcv[li * WCVW + 0  + 8 * g];
        short8 cb1 = *(const short8*)&wcv[li * WCVW + 32 + 8 * g];
        short8 cb2 = *(const short8*)&wcv[li * WCVW + 64 + 8 * g];
        const int fi0   = (g & 1) * 8;
        const int dbase = g >> 1;
        #pragma unroll
        for (int it = 0; it < 9; ++it) {
            int u = wav + 8 * it;
            if (u < NB * 18) {
                int nbu = u / 18, st = u % 18;
                const unsigned short* xsTu = pool + nbu * PBN;
                int s0 = st * 16;
                int rbase = (s0 + li + dbase) * 16 + fi0;
                short8 a0 = *(const short8*)&xsTu[rbase];
                short8 a1 = *(const short8*)&xsTu[rbase + 32];
                short8 a2 = *(const short8*)&xsTu[rbase + 64];
                float4v c = {0.f, 0.f, 0.f, 0.f};
                c = __builtin_amdgcn_mfma_f32_16x16x32_bf16(a0, cb0, c, 0, 0, 0);
                c = __builtin_amdgcn_mfma_f32_16x16x32_bf16(a1, cb1, c, 0, 0, 0);
                c = __builtin_amdgcn_mfma_f32_16x16x32_bf16(a2, cb2, c, 0, 0, 0);
                #pragma unroll
                for (int r = 0; r < 4; ++r) p6o[it][r] = f2b(c[r]);
            }
        }
    }

    // ---- residual pickup from LDS (bf16): xsT intact until cat overwrite ----
    ushort4v res16[9];
    #pragma unroll
    for (int it = 0; it < 9; ++it) {
        int u = wav + 8 * it;
        if (u < NB * 18) {
            int nbu = u / 18, st = u % 18;
            const unsigned short* xsTu = pool + nbu * PBN;
            int s0 = st * 16;
            #pragma unroll
            for (int r = 0; r < 4; ++r)
                res16[it][r] = xsTu[(s0 + 4 * g + r + 2) * 16 + li];
        }
    }
    __syncthreads();   // all pool reads done -> cat may overwrite

    // ---- deferred cat writes (cat aliases each batch pool, stride 32) ----
    {
        #pragma unroll
        for (int m = 0; m < 3; ++m)
            if (m < nt) {
                #pragma unroll
                for (int n = 0; n < NB; ++n) {
                    unsigned short* catn = pool + n * PBN;
                    #pragma unroll
                    for (int r = 0; r < 4; ++r) {
                        int pos = tts[m] * 16 + 4 * g + r;
                        catn[pos * 32 + li] = p5o[m][n][r];
                    }
                }
            }
        #pragma unroll
        for (int it = 0; it < 9; ++it) {
            int u = wav + 8 * it;
            if (u < NB * 18) {
                int nbu = u / 18, st = u % 18;
                unsigned short* catn = pool + nbu * PBN;
                int s0 = st * 16;
                #pragma unroll
                for (int r = 0; r < 4; ++r)
                    catn[(s0 + 4 * g + r) * 32 + 16 + li] = p6o[it][r];
            }
        }
    }
    __syncthreads();

    // ---- P7: fc + bias + residual(bf16, from LDS pickup) via MFMA ----
    {
        short8 fb = *(const short8*)&fcwB[li * 40 + 8 * g];
        #pragma unroll
        for (int it = 0; it < 9; ++it) {
            int u = wav + 8 * it;
            if (u < NB * 18) {
                int nbu = u / 18, st = u % 18;
                const unsigned short* catn = pool + nbu * PBN;
                float* outb = out + (size_t)bid[nbu & 3] * (SEQ * NF);
                int s0 = st * 16;
                float4v c;
                #pragma unroll
                for (int r = 0; r < 4; ++r) c[r] = b2f(res16[it][r]) + fcb[li];
                short8 a = *(const short8*)&catn[(s0 + li) * 32 + 8 * g];
                c = __builtin_amdgcn_mfma_f32_16x16x32_bf16(a, fb, c, 0, 0, 0);
                #pragma unroll
                for (int r = 0; r < 4; ++r) outb[(s0 + 4 * g + r) * 16 + li] = c[r];
            }
        }
    }
}

extern "C" void kernel_launch(void* const* d_in, const int* in_sizes, int n_in,
                              void* d_out, int out_size, void* d_ws, size_t ws_size,
                              hipStream_t stream)
{
    const float* src  = (const float*)d_in[0];
    const int*   eidx = (const int*)  d_in[1];
    const float* Wl   = (const float*)d_in[2];
    const float* Wr   = (const float*)d_in[3];
    const float* bgcn = (const float*)d_in[4];
    const float* cw1  = (const float*)d_in[5];
    const float* cw2  = (const float*)d_in[6];
    const float* fcw  = (const float*)d_in[7];
    const float* fcb  = (const float*)d_in[8];
    float* out = (float*)d_out;

    const int grid = (BTOT + NB - 1) / NB;   // 2144
    const size_t wbytes = (size_t)2 * 288 * 288 * sizeof(unsigned short);
    if (ws_size >= wbytes) {
        wcast_kernel<<<dim3(324), dim3(256), 0, stream>>>(Wl, Wr, (unsigned short*)d_ws);
        stconv_mfma<1><<<dim3(grid), dim3(512), 0, stream>>>(
            src, eidx, Wl, Wr, (const unsigned short*)d_ws,
            bgcn, cw1, cw2, fcw, fcb, out);
    } else {
        stconv_mfma<0><<<dim3(grid), dim3(512), 0, stream>>>(
            src, eidx, Wl, Wr, nullptr,
            bgcn, cw1, cw2, fcw, fcb, out);
    }
}

// Round 22
// 143.086 us; speedup vs baseline: 1.1702x; 1.1702x over previous
//
#include <hip/hip_runtime.h>
#include <hip/hip_bf16.h>

typedef short short8 __attribute__((ext_vector_type(8)));
typedef float float4v __attribute__((ext_vector_type(4)));
typedef unsigned short ushort4v __attribute__((ext_vector_type(4)));

#define BTOT 8576
#define SEQ 288
#define NF 16
#define NB 4
#define SPN 296                 // xsN row stride (ushort)
#define XTROWS 294              // xsT rows: s=-2..291 (idx = s+2)
#define XT_USH (XTROWS * 16)    // 4704
#define XN_USH (16 * SPN)       // 4736
#define PBN (XT_USH + XN_USH)   // 9440 ush per-batch pool; cat (288*32=9216) aliases
#define WCVW 104

__device__ __forceinline__ unsigned short f2b(float f) {
    union { float f; unsigned u; } v; v.f = f;
    unsigned r = v.u + 0x7FFF + ((v.u >> 16) & 1);   // RNE
    return (unsigned short)(r >> 16);
}
__device__ __forceinline__ float b2f(unsigned short u) {
    union { unsigned u; float f; } v; v.u = ((unsigned)u) << 16; return v.f;
}

// one-time Wl/Wr fp32 -> bf16 into workspace (331,776 B)
__global__ void wcast_kernel(const float* __restrict__ a, const float* __restrict__ b,
                             unsigned short* __restrict__ o) {
    int i = blockIdx.x * 256 + threadIdx.x;     // grid 324*256 = 82944 exact
    o[i]         = f2b(a[i]);
    o[82944 + i] = f2b(b[i]);
}

template<int WPRE>
__device__ __forceinline__ short8 ldw(const unsigned short* __restrict__ wb,
                                      const float* __restrict__ wf, int idx) {
    if (WPRE) {
        return *(const short8*)&wb[idx];
    } else {
        const float* p = &wf[idx];
        float4 w0 = *(const float4*)p, w1 = *(const float4*)(p + 4);
        short8 a;
        a[0] = (short)f2b(w0.x); a[1] = (short)f2b(w0.y);
        a[2] = (short)f2b(w0.z); a[3] = (short)f2b(w0.w);
        a[4] = (short)f2b(w1.x); a[5] = (short)f2b(w1.y);
        a[6] = (short)f2b(w1.z); a[7] = (short)f2b(w1.w);
        return a;
    }
}

// B-fragments for all NB batches at K-step KK9 (0..8); same addresses serve x and mean
#define LDB(KK9, B_) do {                                                      \
    const int s0_ = (KK9) * 32;                                                \
    (B_)[0] = *(const short8*)&xsN0[li * SPN + s0_ + 8 * g];                   \
    (B_)[1] = *(const short8*)&xsN1[li * SPN + s0_ + 8 * g];                   \
    (B_)[2] = *(const short8*)&xsN2[li * SPN + s0_ + 8 * g];                   \
    (B_)[3] = *(const short8*)&xsN3[li * SPN + s0_ + 8 * g];                   \
} while (0)

// A-fragments (W rows) for this wave's t-tiles at K-step KK9
#define LDA(WT_, WF_, KK9, A_) do {                                            \
    const int s0_ = (KK9) * 32;                                                \
    _Pragma("unroll")                                                          \
    for (int m_ = 0; m_ < 3; ++m_)                                             \
        if (m_ < nt) (A_)[m_] = ldw<WPRE>(WT_, WF_, arow[m_] + s0_ + 8 * g);   \
} while (0)

#define MFK(A_, B_) do {                                                       \
    _Pragma("unroll")                                                          \
    for (int m_ = 0; m_ < 3; ++m_)                                             \
        if (m_ < nt) {                                                         \
            _Pragma("unroll")                                                  \
            for (int n_ = 0; n_ < NB; ++n_)                                    \
                acc[m_][n_] = __builtin_amdgcn_mfma_f32_16x16x32_bf16((A_)[m_], (B_)[n_], acc[m_][n_], 0, 0, 0); \
        }                                                                      \
} while (0)

// 9 K-steps, 2-deep ping-pong on A only; B read fresh (R20 showed B-pp null)
#define GEMM9(WT_, WF_) do {                                                   \
    short8 aC[3], aN[3];                                                       \
    LDA(WT_, WF_, 0, aC);                                                      \
    LDA(WT_, WF_, 1, aN);                                                      \
    _Pragma("unroll")                                                          \
    for (int kk = 0; kk < 9; ++kk) {                                           \
        short8 bb[NB];                                                         \
        LDB(kk, bb);                                                           \
        if (kk & 1) { MFK(aN, bb); if (kk < 7) LDA(WT_, WF_, kk + 2, aN); }    \
        else        { MFK(aC, bb); if (kk < 7) LDA(WT_, WF_, kk + 2, aC); }    \
    }                                                                          \
} while (0)

template<int WPRE>
__global__ __launch_bounds__(512, 4) void stconv_mfma(
    const float* __restrict__ src,
    const int*   __restrict__ eidx,
    const float* __restrict__ Wlf,
    const float* __restrict__ Wrf,
    const unsigned short* __restrict__ Wbf,
    const float* __restrict__ bgcn,
    const float* __restrict__ cw1g,
    const float* __restrict__ cw2g,
    const float* __restrict__ fcwg,
    const float* __restrict__ fcbg,
    float*       __restrict__ out)
{
    __shared__ unsigned short pool[NB * PBN];  // per batch: [xsT 4704][xsN 4736]; mean in-place; cat aliases
    __shared__ unsigned short wcv[16 * WCVW];
    __shared__ unsigned short fcwB[16 * 40];
    __shared__ unsigned short MB[16 * 40];
    __shared__ float fcb[16];
    // LDS total: 75520*2 + 3328 + 1280 + 1280 + 64 = 81,472 B <= 81,920 (2 blocks/CU)

    const int tid  = threadIdx.x;
    const int wav  = tid >> 6;            // 0..7
    const int lane = tid & 63;
    const int li   = lane & 15;
    const int g    = lane >> 4;
    const int b0   = blockIdx.x * NB;

    int bid[NB];
    #pragma unroll
    for (int n = 0; n < NB; ++n) bid[n] = (b0 + n < BTOT) ? (b0 + n) : (BTOT - 1);

    // ---- P1: zero-init ----
    for (int i = tid; i < 16 * 40; i += 512) MB[i] = 0;
    for (int i = tid; i < 16 * WCVW; i += 512) wcv[i] = 0;
    if (tid < NB * 96) {   // xsT pad rows {0,1,290..293} for all batches
        int nb2 = tid / 96, r2 = tid % 96;
        int r = r2 >> 4, f = r2 & 15;
        int row = (r < 2) ? r : 288 + r;
        pool[nb2 * PBN + row * 16 + f] = 0;
    }
    __syncthreads();

    // ---- P2: x staging as 4x4 blocks, weights, register-based adjacency ----
    {
        #pragma unroll
        for (int i = 0; i < 3; ++i) {
            int u = i * 512 + tid;            // unit = (batch, 4x4 block), NB*288 total
            if (u < NB * 288) {
                int nbu = u / 288, blk = u % 288;
                const float* srcb = src + (size_t)bid[nbu & 3] * (SEQ * NF);
                unsigned short* xsTu = pool + nbu * PBN;
                unsigned short* xsNu = pool + nbu * PBN + XT_USH;
                int s0 = (blk >> 2) * 4, f0 = (blk & 3) * 4;
                ushort4v h[4];
                #pragma unroll
                for (int r = 0; r < 4; ++r) {
                    float4 v = *(const float4*)(srcb + (s0 + r) * 16 + f0);
                    h[r][0] = f2b(v.x); h[r][1] = f2b(v.y);
                    h[r][2] = f2b(v.z); h[r][3] = f2b(v.w);
                    *(ushort4v*)&xsTu[(s0 + r + 2) * 16 + f0] = h[r];
                }
                #pragma unroll
                for (int c = 0; c < 4; ++c) {  // transposed rows: pure repack
                    ushort4v w;
                    w[0] = h[0][c]; w[1] = h[1][c]; w[2] = h[2][c]; w[3] = h[3][c];
                    *(ushort4v*)&xsNu[(f0 + c) * SPN + s0] = w;
                }
            }
        }
    }
    for (int j = tid; j < 1280; j += 512) {       // fused conv taps: T[d]=w2[d]+w1[d-1]
        int fo = j / 80, rem = j % 80, fi = rem / 5, d = rem % 5;
        float t = cw2g[(fo * 16 + fi) * 5 + d];
        if (d >= 1 && d <= 3) t += cw1g[(fo * 16 + fi) * 3 + (d - 1)];
        wcv[fo * WCVW + d * 16 + fi] = f2b(t);
    }
    if (tid < 512) fcwB[(tid >> 5) * 40 + (tid & 31)] = f2b(fcwg[tid]);
    if (tid < 16) fcb[tid] = fcbg[tid];
    // adjacency in registers: thread (d,f) counts edges, shfl-reduce for degree
    if (tid < 256) {
        const int d = tid >> 4, f = tid & 15;
        float cnt = 0.0f;
        for (int e = 0; e < 96; ++e) {
            int es = eidx[e], ed = eidx[96 + e];
            cnt += (ed == d && es == f) ? 1.0f : 0.0f;
        }
        float deg = cnt;
        #pragma unroll
        for (int off = 1; off < 16; off <<= 1) deg += __shfl_xor(deg, off);
        MB[d * 40 + f] = f2b(cnt / fmaxf(deg, 1.0f));   // cols 16..39 remain zero
    }
    __syncthreads();

    // wave -> t-tile assignment: all 18 tiles covered exactly once
    const int t2 = (wav == 0) ? 16 : ((wav == 5) ? 17 : -1);
    const int nt = (t2 >= 0) ? 3 : 2;
    const int tts[3] = {wav, wav + 8, t2};
    const int arow[3] = {(tts[0] * 16 + li) * 288, (tts[1] * 16 + li) * 288,
                         (t2 >= 0) ? ((t2 * 16 + li) * 288) : 0};

    const unsigned short* WblT = Wbf;
    const unsigned short* WbrT = Wbf + 288 * 288;
    const unsigned short* xsN0 = pool + 0 * PBN + XT_USH;
    const unsigned short* xsN1 = pool + 1 * PBN + XT_USH;
    const unsigned short* xsN2 = pool + 2 * PBN + XT_USH;
    const unsigned short* xsN3 = pool + 3 * PBN + XT_USH;

    float4v acc[3][NB];   // carries H then feat (AGPRs); held through the epilogue

    // ---- P5a: acc = Wr*x + bias (bias read from L2-cached bgcn) ----
    #pragma unroll
    for (int m = 0; m < 3; ++m)
        if (m < nt) {
            #pragma unroll
            for (int r = 0; r < 4; ++r) {
                float bv = bgcn[tts[m] * 16 + 4 * g + r];
                #pragma unroll
                for (int n = 0; n < NB; ++n) acc[m][n][r] = bv;
            }
        }
    GEMM9(WbrT, Wrf);
    __syncthreads();   // all xsN reads done -> mean may overwrite in place

    // ---- P4': mean = M * x, in-place into xsN slots (units = batch x st) ----
    {
        short8 bm = *(const short8*)&MB[li * 40 + 8 * g];
        #pragma unroll
        for (int it = 0; it < 9; ++it) {
            int u = wav + 8 * it;
            if (u < NB * 18) {
                int nbu = u / 18, st = u % 18;
                unsigned short* xsTu = pool + nbu * PBN;
                unsigned short* msNu = pool + nbu * PBN + XT_USH;
                int s0 = st * 16;
                short8 a = {0, 0, 0, 0, 0, 0, 0, 0};
                if (g < 2) a = *(const short8*)&xsTu[(s0 + li + 2) * 16 + 8 * g];
                float4v c = {0.f, 0.f, 0.f, 0.f};
                c = __builtin_amdgcn_mfma_f32_16x16x32_bf16(a, bm, c, 0, 0, 0);
                ushort4v p;
                #pragma unroll
                for (int r = 0; r < 4; ++r) p[r] = f2b(c[r]);
                *(ushort4v*)&msNu[li * SPN + s0 + 4 * g] = p;
            }
        }
    }
    __syncthreads();

    // ---- P5b: acc += Wl*mean (same B addresses) ----
    GEMM9(WblT, Wlf);

    // ---- per-batch epilogue: {P6(n)+res(n); bar; cat(n); bar; P7(n)} ----
    // acc stays in AGPRs; f2b(acc) at write time; per-batch arrays only (no spill)
    {
        short8 cb0 = *(const short8*)&wcv[li * WCVW + 0  + 8 * g];
        short8 cb1 = *(const short8*)&wcv[li * WCVW + 32 + 8 * g];
        short8 cb2 = *(const short8*)&wcv[li * WCVW + 64 + 8 * g];
        short8 fb  = *(const short8*)&fcwB[li * 40 + 8 * g];
        const int fi0   = (g & 1) * 8;
        const int dbase = g >> 1;
        #pragma unroll
        for (int n = 0; n < NB; ++n) {
            unsigned short* pooln = pool + n * PBN;
            ushort4v p6o[3], rr[3];
            #pragma unroll
            for (int it = 0; it < 3; ++it) {
                int st = wav + 8 * it;
                if (st < 18) {
                    int s0 = st * 16;
                    int rbase = (s0 + li + dbase) * 16 + fi0;
                    short8 a0 = *(const short8*)&pooln[rbase];
                    short8 a1 = *(const short8*)&pooln[rbase + 32];
                    short8 a2 = *(const short8*)&pooln[rbase + 64];
                    float4v c = {0.f, 0.f, 0.f, 0.f};
                    c = __builtin_amdgcn_mfma_f32_16x16x32_bf16(a0, cb0, c, 0, 0, 0);
                    c = __builtin_amdgcn_mfma_f32_16x16x32_bf16(a1, cb1, c, 0, 0, 0);
                    c = __builtin_amdgcn_mfma_f32_16x16x32_bf16(a2, cb2, c, 0, 0, 0);
                    #pragma unroll
                    for (int r = 0; r < 4; ++r) {
                        p6o[it][r] = f2b(c[r]);
                        rr[it][r]  = pooln[(s0 + 4 * g + r + 2) * 16 + li];
                    }
                }
            }
            __syncthreads();   // all pool[n] reads complete -> cat(n) may overwrite
            #pragma unroll
            for (int m = 0; m < 3; ++m)
                if (m < nt) {
                    #pragma unroll
                    for (int r = 0; r < 4; ++r) {
                        int pos = tts[m] * 16 + 4 * g + r;
                        pooln[pos * 32 + li] = f2b(acc[m][n][r]);
                    }
                }
            #pragma unroll
            for (int it = 0; it < 3; ++it) {
                int st = wav + 8 * it;
                if (st < 18) {
                    int s0 = st * 16;
                    #pragma unroll
                    for (int r = 0; r < 4; ++r)
                        pooln[(s0 + 4 * g + r) * 32 + 16 + li] = p6o[it][r];
                }
            }
            __syncthreads();   // cat(n) visible
            float* outb = out + (size_t)bid[n] * (SEQ * NF);
            #pragma unroll
            for (int it = 0; it < 3; ++it) {
                int st = wav + 8 * it;
                if (st < 18) {
                    int s0 = st * 16;
                    float4v c;
                    #pragma unroll
                    for (int r = 0; r < 4; ++r) c[r] = b2f(rr[it][r]) + fcb[li];
                    short8 a = *(const short8*)&pooln[(s0 + li) * 32 + 8 * g];
                    c = __builtin_amdgcn_mfma_f32_16x16x32_bf16(a, fb, c, 0, 0, 0);
                    #pragma unroll
                    for (int r = 0; r < 4; ++r) outb[(s0 + 4 * g + r) * 16 + li] = c[r];
                }
            }
        }
    }
}

extern "C" void kernel_launch(void* const* d_in, const int* in_sizes, int n_in,
                              void* d_out, int out_size, void* d_ws, size_t ws_size,
                              hipStream_t stream)
{
    const float* src  = (const float*)d_in[0];
    const int*   eidx = (const int*)  d_in[1];
    const float* Wl   = (const float*)d_in[2];
    const float* Wr   = (const float*)d_in[3];
    const float* bgcn = (const float*)d_in[4];
    const float* cw1  = (const float*)d_in[5];
    const float* cw2  = (const float*)d_in[6];
    const float* fcw  = (const float*)d_in[7];
    const float* fcb  = (const float*)d_in[8];
    float* out = (float*)d_out;

    const int grid = (BTOT + NB - 1) / NB;   // 2144
    const size_t wbytes = (size_t)2 * 288 * 288 * sizeof(unsigned short);
    if (ws_size >= wbytes) {
        wcast_kernel<<<dim3(324), dim3(256), 0, stream>>>(Wl, Wr, (unsigned short*)d_ws);
        stconv_mfma<1><<<dim3(grid), dim3(512), 0, stream>>>(
            src, eidx, Wl, Wr, (const unsigned short*)d_ws,
            bgcn, cw1, cw2, fcw, fcb, out);
    } else {
        stconv_mfma<0><<<dim3(grid), dim3(512), 0, stream>>>(
            src, eidx, Wl, Wr, nullptr,
            bgcn, cw1, cw2, fcw, fcb, out);
    }
}